// Round 12
// baseline (633.079 us; speedup 1.0000x reference)
//
#include <hip/hip_runtime.h>
#include <math.h>

#define NB 32
#define M 2048
#define N 1536
#define NORD 6

// ---- output offsets (flat fp32, reference return order) ----
#define OFF_COEFFS 0
#define OFF_RHS    49152
#define OFF_NSX    57344
#define OFF_NSY    57824
#define OFF_ATA    58304
#define OFF_ATPRHS 75555776
#define OFF_D      75604928
#define OFF_L      75654080
#define OFF_U      151151552
#define SMALL_TOTAL 58304

typedef short short8v __attribute__((ext_vector_type(8)));
typedef float f32x4 __attribute__((ext_vector_type(4)));

__device__ __forceinline__ uint rtn_bf16(float x) {
    uint u = __float_as_uint(x);
    return (u + 0x7fffu + ((u >> 16) & 1u)) >> 16;   // round-to-nearest-even bf16
}

// nontemporal stores (round-5: -57us confirmed win)
__device__ __forceinline__ void nts(float v, float* p) {
    __builtin_nontemporal_store(v, p);
}
__device__ __forceinline__ void nts4(f32x4 v, float* p) {
    __builtin_nontemporal_store(v, (f32x4*)p);
}

// ---------------- small stuff: downsample coeffs/rhs, pair-sum steps ----------------
__global__ void small_kernel(const float* __restrict__ coeffs,
                             const float* __restrict__ rhs,
                             const float* __restrict__ sx,
                             const float* __restrict__ sy,
                             float* __restrict__ out) {
    int idx = blockIdx.x * blockDim.x + threadIdx.x;
    if (idx >= SMALL_TOTAL) return;
    const float scale = 31.0f / 15.0f;  // align_corners=True, 32 -> 16
    if (idx < 49152) {
        int b = idx / 1536;
        int rem = idx % 1536;
        int gp = rem / 6;
        int o  = rem % 6;
        int yy = gp / 16, xx = gp % 16;
        float py = (float)yy * scale;
        int ly = (int)floorf(py); if (ly > 30) ly = 30;
        float wy = py - (float)ly;
        float px = (float)xx * scale;
        int lx = (int)floorf(px); if (lx > 30) lx = 30;
        float wx = px - (float)lx;
        const float* base = coeffs + (size_t)b * 1024 * NORD;
        float v00 = base[(ly * 32 + lx) * NORD + o];
        float v01 = base[(ly * 32 + lx + 1) * NORD + o];
        float v10 = base[((ly + 1) * 32 + lx) * NORD + o];
        float v11 = base[((ly + 1) * 32 + lx + 1) * NORD + o];
        float a  = v00 * (1.0f - wy) + v10 * wy;
        float bb = v01 * (1.0f - wy) + v11 * wy;
        out[OFF_COEFFS + idx] = a * (1.0f - wx) + bb * wx;
    } else if (idx < 57344) {
        int j = idx - 49152;
        int b = j / 256;
        int gp = j % 256;
        int yy = gp / 16, xx = gp % 16;
        float py = (float)yy * scale;
        int ly = (int)floorf(py); if (ly > 30) ly = 30;
        float wy = py - (float)ly;
        float px = (float)xx * scale;
        int lx = (int)floorf(px); if (lx > 30) lx = 30;
        float wx = px - (float)lx;
        const float* base = rhs + (size_t)b * 1024;
        float v00 = base[ly * 32 + lx];
        float v01 = base[ly * 32 + lx + 1];
        float v10 = base[(ly + 1) * 32 + lx];
        float v11 = base[(ly + 1) * 32 + lx + 1];
        float a  = v00 * (1.0f - wy) + v10 * wy;
        float bb = v01 * (1.0f - wy) + v11 * wy;
        out[OFF_RHS + j] = a * (1.0f - wx) + bb * wx;
    } else if (idx < 57824) {
        int j = idx - 57344;
        int b = j / 15, k = j % 15;
        out[OFF_NSX + j] = sx[b * 31 + 2 * k] + sx[b * 31 + 2 * k + 1];
    } else {
        int j = idx - 57824;
        int b = j / 15, k = j % 15;
        out[OFF_NSY + j] = sy[b * 31 + 2 * k] + sy[b * 31 + 2 * k + 1];
    }
}

// ---------------- split A -> RTN bf16 (granule layout) + partial AtPrhs/D ----------------
// Ahi layout: [b][oct=m/8][col][8] ushort  (16B granule per (oct,col))
__global__ __launch_bounds__(256) void split_kernel(const float* __restrict__ A,
                                                    const float* __restrict__ Arhs,
                                                    ushort* __restrict__ Ahi,
                                                    float2* __restrict__ part) {
    int bid = blockIdx.x;
    int q  = bid & 3;
    int cb = (bid >> 2) % 6;
    int b  = bid / 24;
    int t  = threadIdx.x;
    int col = cb * 256 + t;
    const float* Ab = A + (size_t)b * M * N;
    const float* rb = Arhs + (size_t)b * M;
    uint4* Hp = (uint4*)Ahi;
    float s1 = 0.0f, s2 = 0.0f;
    for (int oct = q * 64; oct < q * 64 + 64; ++oct) {
        uint hw[4];
#pragma unroll
        for (int j = 0; j < 4; ++j) {
            float a0 = Ab[(size_t)(oct * 8 + 2 * j) * N + col];
            float a1 = Ab[(size_t)(oct * 8 + 2 * j + 1) * N + col];
            float r0 = rb[oct * 8 + 2 * j];
            float r1 = rb[oct * 8 + 2 * j + 1];
            s1 = fmaf(a0, r0, s1); s1 = fmaf(a1, r1, s1);
            s2 = fmaf(a0, a0, s2); s2 = fmaf(a1, a1, s2);
            hw[j] = rtn_bf16(a0) | (rtn_bf16(a1) << 16);
        }
        Hp[(size_t)(b * 256 + oct) * N + col] = make_uint4(hw[0], hw[1], hw[2], hw[3]);
    }
    part[(size_t)q * (NB * 6 * 256) + (size_t)(b * 6 + cb) * 256 + t] = make_float2(s1, s2);
}

__global__ __launch_bounds__(256) void reduce_kernel(const float2* __restrict__ part,
                                                     float* __restrict__ out) {
    int idx = blockIdx.x * 256 + threadIdx.x;   // 0..49151 == b*N + col
    float s1 = 0.0f, s2 = 0.0f;
#pragma unroll
    for (int q = 0; q < 4; ++q) {
        float2 p = part[(size_t)q * (NB * 6 * 256) + idx];
        s1 += p.x; s2 += p.y;
    }
    out[OFF_ATPRHS + idx] = s1;
    out[OFF_D + idx] = s2;
}

// ---------------- 1-pass bf16 MFMA SYRK: register-direct, NO LDS, NO barriers ----------------
// 128x128 pair tile, 256 thr (2x2 waves), wave-tile 64x64. Each wave loads its MFMA
// fragments straight from global (16B granule == one fragment; lanes 0-15 = 256B
// contiguous -> coalesced, L1/L2-served). Register double-buffer, waves fully async.
#define SYRKR_BLOCKS (NB * 78)   // 2496, %8 == 0
#define KSTRIDE (4 * N * 16)     // bytes per K-32 step in granule layout: 98304

__global__ __launch_bounds__(256, 2) void syrkr_kernel(const ushort* __restrict__ Ahi,
                                                       float* __restrict__ out) {
    int bid = blockIdx.x;
    int swz = (bid % 8) * (SYRKR_BLOCKS / 8) + bid / 8;   // XCD-chunked, bijective
    int b = swz / 78;
    int p = swz % 78;
    int ti = 0;
    while ((ti + 1) * (ti + 2) / 2 <= p) ++ti;
    int tj = p - ti * (ti + 1) / 2;
    bool diag = (ti == tj);
    int i0 = ti * 128, j0 = tj * 128;

    int t = threadIdx.x, w = t >> 6, l = t & 63;
    int wr = w >> 1, wc = w & 1;                // 2x2 wave grid, wave-tile 64x64
    int lc = l & 15, lg = l >> 4;

    const char* base = (const char*)(Ahi + (size_t)b * 256 * N * 8);
    // lane fragment pointers: byte = ((oct)*N + col)*16, oct=lg folded in, ai/bj via imm offset
    const char* pa = base + ((size_t)lg * N + i0 + wr * 64 + lc) * 16;
    const char* pb = base + ((size_t)lg * N + j0 + wc * 64 + lc) * 16;

    f32x4 acc[4][4];
#pragma unroll
    for (int i = 0; i < 4; ++i)
#pragma unroll
        for (int j = 0; j < 4; ++j)
#pragma unroll
            for (int k = 0; k < 4; ++k) acc[i][j][k] = 0.0f;

    short8v A0[4], B0[4], A1[4], B1[4];
#pragma unroll
    for (int i = 0; i < 4; ++i) {               // preload steps 0 and 1
        A0[i] = *(const short8v*)(pa + i * 256);
        B0[i] = *(const short8v*)(pb + i * 256);
        A1[i] = *(const short8v*)(pa + KSTRIDE + i * 256);
        B1[i] = *(const short8v*)(pb + KSTRIDE + i * 256);
    }
    const char* paN  = pa + 2 * (size_t)KSTRIDE;   // -> f(s+2)
    const char* pbN  = pb + 2 * (size_t)KSTRIDE;
    const char* paN1 = pa + 3 * (size_t)KSTRIDE;   // -> f(s+3)
    const char* pbN1 = pb + 3 * (size_t)KSTRIDE;

    for (int s = 0; s < 62; s += 2) {
        // compute step s with A0/B0
#pragma unroll
        for (int ai = 0; ai < 4; ++ai)
#pragma unroll
            for (int bj = 0; bj < 4; ++bj)
                acc[ai][bj] = __builtin_amdgcn_mfma_f32_16x16x32_bf16(A0[ai], B0[bj], acc[ai][bj], 0, 0, 0);
        // refill A0/B0 with f(s+2) — lands while f(s+1) computes
#pragma unroll
        for (int i = 0; i < 4; ++i) {
            A0[i] = *(const short8v*)(paN + i * 256);
            B0[i] = *(const short8v*)(pbN + i * 256);
        }
        paN += 2 * (size_t)KSTRIDE; pbN += 2 * (size_t)KSTRIDE;

        // compute step s+1 with A1/B1
#pragma unroll
        for (int ai = 0; ai < 4; ++ai)
#pragma unroll
            for (int bj = 0; bj < 4; ++bj)
                acc[ai][bj] = __builtin_amdgcn_mfma_f32_16x16x32_bf16(A1[ai], B1[bj], acc[ai][bj], 0, 0, 0);
        // refill A1/B1 with f(s+3)
#pragma unroll
        for (int i = 0; i < 4; ++i) {
            A1[i] = *(const short8v*)(paN1 + i * 256);
            B1[i] = *(const short8v*)(pbN1 + i * 256);
        }
        paN1 += 2 * (size_t)KSTRIDE; pbN1 += 2 * (size_t)KSTRIDE;
    }
    // epilogue: steps 62 (A0/B0) and 63 (A1/B1), no further loads
#pragma unroll
    for (int ai = 0; ai < 4; ++ai)
#pragma unroll
        for (int bj = 0; bj < 4; ++bj)
            acc[ai][bj] = __builtin_amdgcn_mfma_f32_16x16x32_bf16(A0[ai], B0[bj], acc[ai][bj], 0, 0, 0);
#pragma unroll
    for (int ai = 0; ai < 4; ++ai)
#pragma unroll
        for (int bj = 0; bj < 4; ++bj)
            acc[ai][bj] = __builtin_amdgcn_mfma_f32_16x16x32_bf16(A1[ai], B1[bj], acc[ai][bj], 0, 0, 0);

    float* AtA = out + OFF_ATA + (size_t)b * N * N;
    float* Lo  = out + OFF_L   + (size_t)b * N * N;
    float* Up  = out + OFF_U   + (size_t)b * N * N;

#pragma unroll
    for (int ai = 0; ai < 4; ++ai) {
        int gi0 = i0 + wr * 64 + ai * 16 + lg * 4;
#pragma unroll
        for (int bj = 0; bj < 4; ++bj) {
            int gj = j0 + wc * 64 + bj * 16 + lc;
#pragma unroll
            for (int r = 0; r < 4; ++r) {
                int gi = gi0 + r;
                float v = acc[ai][bj][r];
                size_t o = (size_t)gi * N + gj;
                nts(v, AtA + o);
                nts((gj <= gi) ? v : 0.0f, Lo + o);
                nts((gj >  gi) ? v : 0.0f, Up + o);
            }
            if (!diag) {                        // mirror: float4 over r (contiguous gi)
                f32x4 va = acc[ai][bj], vl, vu;
#pragma unroll
                for (int r = 0; r < 4; ++r) {
                    int gi = gi0 + r;
                    vl[r] = (gi <= gj) ? va[r] : 0.0f;
                    vu[r] = (gi >  gj) ? va[r] : 0.0f;
                }
                size_t om = (size_t)gj * N + gi0;
                nts4(va, AtA + om);
                nts4(vl, Lo  + om);
                nts4(vu, Up  + om);
            }
        }
    }
}

// ---------------- fp32 fallback (round-1, known-good) ----------------
__global__ __launch_bounds__(256) void atp_d_kernel(const float* __restrict__ A,
                                                    const float* __restrict__ Arhs,
                                                    float* __restrict__ out) {
    int b  = blockIdx.x / 6;
    int cb = blockIdx.x % 6;
    int col = cb * 256 + threadIdx.x;
    const float* Ab = A + (size_t)b * M * N;
    const float* rb = Arhs + (size_t)b * M;
    float s1 = 0.0f, s2 = 0.0f;
#pragma unroll 4
    for (int m = 0; m < M; ++m) {
        float a = Ab[(size_t)m * N + col];
        float r = rb[m];
        s1 = fmaf(a, r, s1);
        s2 = fmaf(a, a, s2);
    }
    out[OFF_ATPRHS + b * N + col] = s1;
    out[OFF_D      + b * N + col] = s2;
}

#define BM 128
#define BK 16
#define NPAIRS 78

__global__ __launch_bounds__(256, 2) void syrk_kernel(const float* __restrict__ A,
                                                      float* __restrict__ out) {
    __shared__ float As[BK][BM];
    __shared__ float Bs[BK][BM];

    int bid = blockIdx.x;
    int b = bid / NPAIRS;
    int p = bid % NPAIRS;
    int ti = (int)((sqrtf(8.0f * (float)p + 1.0f) - 1.0f) * 0.5f);
    while ((ti + 1) * (ti + 2) / 2 <= p) ++ti;
    while (ti * (ti + 1) / 2 > p) --ti;
    int tj = p - ti * (ti + 1) / 2;
    int i0 = ti * BM, j0 = tj * BM;

    const float* Ab = A + (size_t)b * M * N;
    int t = threadIdx.x;
    int tx = t % 16, ty = t / 16;
    int lcv = (t % 32) * 4;
    int lk = t / 32;

    float acc[2][4][2][4] = {};

    for (int m0 = 0; m0 < M; m0 += BK) {
        const float* pa = Ab + (size_t)(m0 + lk) * N;
        float4 a0 = *(const float4*)(pa + i0 + lcv);
        float4 a1 = *(const float4*)(pa + (size_t)8 * N + i0 + lcv);
        float4 b0 = *(const float4*)(pa + j0 + lcv);
        float4 b1 = *(const float4*)(pa + (size_t)8 * N + j0 + lcv);
        *(float4*)&As[lk][lcv]     = a0;
        *(float4*)&As[lk + 8][lcv] = a1;
        *(float4*)&Bs[lk][lcv]     = b0;
        *(float4*)&Bs[lk + 8][lcv] = b1;
        __syncthreads();
#pragma unroll
        for (int kk = 0; kk < BK; ++kk) {
            float ar[2][4], br[2][4];
            *(float4*)&ar[0][0] = *(const float4*)&As[kk][ty * 4];
            *(float4*)&ar[1][0] = *(const float4*)&As[kk][64 + ty * 4];
            *(float4*)&br[0][0] = *(const float4*)&Bs[kk][tx * 4];
            *(float4*)&br[1][0] = *(const float4*)&Bs[kk][64 + tx * 4];
#pragma unroll
            for (int rh = 0; rh < 2; ++rh)
#pragma unroll
                for (int r = 0; r < 4; ++r)
#pragma unroll
                    for (int ch = 0; ch < 2; ++ch)
#pragma unroll
                        for (int c = 0; c < 4; ++c)
                            acc[rh][r][ch][c] = fmaf(ar[rh][r], br[ch][c], acc[rh][r][ch][c]);
        }
        __syncthreads();
    }

    float* AtA = out + OFF_ATA + (size_t)b * N * N;
    float* L   = out + OFF_L   + (size_t)b * N * N;
    float* U   = out + OFF_U   + (size_t)b * N * N;

#pragma unroll
    for (int rh = 0; rh < 2; ++rh)
#pragma unroll
        for (int r = 0; r < 4; ++r) {
            int gi = i0 + rh * 64 + ty * 4 + r;
#pragma unroll
            for (int ch = 0; ch < 2; ++ch) {
                int gjb = j0 + ch * 64 + tx * 4;
                float ta[4], tl[4], tu[4];
#pragma unroll
                for (int c = 0; c < 4; ++c) {
                    int gj = gjb + c;
                    float v = acc[rh][r][ch][c];
                    ta[c] = v;
                    tl[c] = (gj <= gi) ? v : 0.0f;
                    tu[c] = (gj >  gi) ? v : 0.0f;
                }
                size_t o = (size_t)gi * N + gjb;
                *(float4*)(AtA + o) = *(float4*)ta;
                *(float4*)(L   + o) = *(float4*)tl;
                *(float4*)(U   + o) = *(float4*)tu;
            }
        }

    if (ti != tj) {
#pragma unroll
        for (int ch = 0; ch < 2; ++ch)
#pragma unroll
            for (int c = 0; c < 4; ++c) {
                int gj = j0 + ch * 64 + tx * 4 + c;
#pragma unroll
                for (int rh = 0; rh < 2; ++rh) {
                    int gib = i0 + rh * 64 + ty * 4;
                    float ta[4], tl[4], tu[4];
#pragma unroll
                    for (int r = 0; r < 4; ++r) {
                        int gi = gib + r;
                        float v = acc[rh][r][ch][c];
                        ta[r] = v;
                        tl[r] = (gi <= gj) ? v : 0.0f;
                        tu[r] = (gi >  gj) ? v : 0.0f;
                    }
                    size_t o = (size_t)gj * N + gib;
                    *(float4*)(AtA + o) = *(float4*)ta;
                    *(float4*)(L   + o) = *(float4*)tl;
                    *(float4*)(U   + o) = *(float4*)tu;
                }
            }
    }
}

extern "C" void kernel_launch(void* const* d_in, const int* in_sizes, int n_in,
                              void* d_out, int out_size, void* d_ws, size_t ws_size,
                              hipStream_t stream) {
    const float* coeffs = (const float*)d_in[0];
    const float* rhs    = (const float*)d_in[1];
    const float* sx     = (const float*)d_in[2];
    const float* sy     = (const float*)d_in[3];
    const float* A      = (const float*)d_in[4];
    const float* Arhs   = (const float*)d_in[5];
    float* out = (float*)d_out;

    small_kernel<<<(SMALL_TOTAL + 255) / 256, 256, 0, stream>>>(coeffs, rhs, sx, sy, out);

    const size_t hi_bytes   = (size_t)NB * M * N * sizeof(ushort);       // 201,326,592
    const size_t part_bytes = (size_t)4 * NB * 6 * 256 * sizeof(float2); // 1,572,864
    if (ws_size >= hi_bytes + part_bytes) {
        ushort* Ahi  = (ushort*)d_ws;
        float2* part = (float2*)((char*)d_ws + hi_bytes);
        split_kernel<<<768, 256, 0, stream>>>(A, Arhs, Ahi, part);
        reduce_kernel<<<192, 256, 0, stream>>>(part, out);
        syrkr_kernel<<<SYRKR_BLOCKS, 256, 0, stream>>>(Ahi, out);
    } else {
        atp_d_kernel<<<NB * 6, 256, 0, stream>>>(A, Arhs, out);
        syrk_kernel<<<NB * NPAIRS, 256, 0, stream>>>(A, out);
    }
}

// Round 13
// 514.256 us; speedup vs baseline: 1.2311x; 1.2311x over previous
//
#include <hip/hip_runtime.h>
#include <math.h>

#define NB 32
#define M 2048
#define N 1536
#define NORD 6

// ---- output offsets (flat fp32, reference return order) ----
#define OFF_COEFFS 0
#define OFF_RHS    49152
#define OFF_NSX    57344
#define OFF_NSY    57824
#define OFF_ATA    58304
#define OFF_ATPRHS 75555776
#define OFF_D      75604928
#define OFF_L      75654080
#define OFF_U      151151552
#define SMALL_TOTAL 58304

typedef short short8v __attribute__((ext_vector_type(8)));
typedef float f32x4 __attribute__((ext_vector_type(4)));

__device__ __forceinline__ void gload16(const void* g, void* l) {
    __builtin_amdgcn_global_load_lds(
        (const __attribute__((address_space(1))) void*)g,
        (__attribute__((address_space(3))) void*)l, 16, 0, 0);
}

__device__ __forceinline__ uint rtn_bf16(float x) {
    uint u = __float_as_uint(x);
    return (u + 0x7fffu + ((u >> 16) & 1u)) >> 16;   // round-to-nearest-even bf16
}

// nontemporal stores (round-5: -57us confirmed win)
__device__ __forceinline__ void nts(float v, float* p) {
    __builtin_nontemporal_store(v, p);
}
__device__ __forceinline__ void nts4(f32x4 v, float* p) {
    __builtin_nontemporal_store(v, (f32x4*)p);
}

// ---------------- small stuff: downsample coeffs/rhs, pair-sum steps ----------------
__global__ void small_kernel(const float* __restrict__ coeffs,
                             const float* __restrict__ rhs,
                             const float* __restrict__ sx,
                             const float* __restrict__ sy,
                             float* __restrict__ out) {
    int idx = blockIdx.x * blockDim.x + threadIdx.x;
    if (idx >= SMALL_TOTAL) return;
    const float scale = 31.0f / 15.0f;  // align_corners=True, 32 -> 16
    if (idx < 49152) {
        int b = idx / 1536;
        int rem = idx % 1536;
        int gp = rem / 6;
        int o  = rem % 6;
        int yy = gp / 16, xx = gp % 16;
        float py = (float)yy * scale;
        int ly = (int)floorf(py); if (ly > 30) ly = 30;
        float wy = py - (float)ly;
        float px = (float)xx * scale;
        int lx = (int)floorf(px); if (lx > 30) lx = 30;
        float wx = px - (float)lx;
        const float* base = coeffs + (size_t)b * 1024 * NORD;
        float v00 = base[(ly * 32 + lx) * NORD + o];
        float v01 = base[(ly * 32 + lx + 1) * NORD + o];
        float v10 = base[((ly + 1) * 32 + lx) * NORD + o];
        float v11 = base[((ly + 1) * 32 + lx + 1) * NORD + o];
        float a  = v00 * (1.0f - wy) + v10 * wy;
        float bb = v01 * (1.0f - wy) + v11 * wy;
        out[OFF_COEFFS + idx] = a * (1.0f - wx) + bb * wx;
    } else if (idx < 57344) {
        int j = idx - 49152;
        int b = j / 256;
        int gp = j % 256;
        int yy = gp / 16, xx = gp % 16;
        float py = (float)yy * scale;
        int ly = (int)floorf(py); if (ly > 30) ly = 30;
        float wy = py - (float)ly;
        float px = (float)xx * scale;
        int lx = (int)floorf(px); if (lx > 30) lx = 30;
        float wx = px - (float)lx;
        const float* base = rhs + (size_t)b * 1024;
        float v00 = base[ly * 32 + lx];
        float v01 = base[ly * 32 + lx + 1];
        float v10 = base[(ly + 1) * 32 + lx];
        float v11 = base[(ly + 1) * 32 + lx + 1];
        float a  = v00 * (1.0f - wy) + v10 * wy;
        float bb = v01 * (1.0f - wy) + v11 * wy;
        out[OFF_RHS + j] = a * (1.0f - wx) + bb * wx;
    } else if (idx < 57824) {
        int j = idx - 57344;
        int b = j / 15, k = j % 15;
        out[OFF_NSX + j] = sx[b * 31 + 2 * k] + sx[b * 31 + 2 * k + 1];
    } else {
        int j = idx - 57824;
        int b = j / 15, k = j % 15;
        out[OFF_NSY + j] = sy[b * 31 + 2 * k] + sy[b * 31 + 2 * k + 1];
    }
}

// ---------------- split A -> RTN bf16 (granule layout) + partial AtPrhs/D ----------------
// Ahi layout: [b][oct=m/8][col][8] ushort  (16B granule per (oct,col))
__global__ __launch_bounds__(256) void split_kernel(const float* __restrict__ A,
                                                    const float* __restrict__ Arhs,
                                                    ushort* __restrict__ Ahi,
                                                    float2* __restrict__ part) {
    int bid = blockIdx.x;
    int q  = bid & 3;
    int cb = (bid >> 2) % 6;
    int b  = bid / 24;
    int t  = threadIdx.x;
    int col = cb * 256 + t;
    const float* Ab = A + (size_t)b * M * N;
    const float* rb = Arhs + (size_t)b * M;
    uint4* Hp = (uint4*)Ahi;
    float s1 = 0.0f, s2 = 0.0f;
    for (int oct = q * 64; oct < q * 64 + 64; ++oct) {
        uint hw[4];
#pragma unroll
        for (int j = 0; j < 4; ++j) {
            float a0 = Ab[(size_t)(oct * 8 + 2 * j) * N + col];
            float a1 = Ab[(size_t)(oct * 8 + 2 * j + 1) * N + col];
            float r0 = rb[oct * 8 + 2 * j];
            float r1 = rb[oct * 8 + 2 * j + 1];
            s1 = fmaf(a0, r0, s1); s1 = fmaf(a1, r1, s1);
            s2 = fmaf(a0, a0, s2); s2 = fmaf(a1, a1, s2);
            hw[j] = rtn_bf16(a0) | (rtn_bf16(a1) << 16);
        }
        Hp[(size_t)(b * 256 + oct) * N + col] = make_uint4(hw[0], hw[1], hw[2], hw[3]);
    }
    part[(size_t)q * (NB * 6 * 256) + (size_t)(b * 6 + cb) * 256 + t] = make_float2(s1, s2);
}

__global__ __launch_bounds__(256) void reduce_kernel(const float2* __restrict__ part,
                                                     float* __restrict__ out) {
    int idx = blockIdx.x * 256 + threadIdx.x;   // 0..49151 == b*N + col
    float s1 = 0.0f, s2 = 0.0f;
#pragma unroll
    for (int q = 0; q < 4; ++q) {
        float2 p = part[(size_t)q * (NB * 6 * 256) + idx];
        s1 += p.x; s2 += p.y;
    }
    out[OFF_ATPRHS + idx] = s1;
    out[OFF_D + idx] = s2;
}

// ---------------- 1-pass bf16 MFMA SYRK, depth-3 rotating pipeline (round-6 best body) ----------------
// tile = 256 rows x 128 cols (pair-half), 8 waves (4x2), wave-tile 64x64, BK=32.
// 3 LDS buffers, prefetch 2 K-steps ahead, counted vmcnt. Diag tiles stage only the
// i-panel (2 loads/wave) and read B from it at half*128 offset (rounds 2-3 verified path).
#define SYRK_BLOCKS (NB * 42)   // 1344

__global__ __launch_bounds__(512, 4) void syrk1_kernel(const ushort* __restrict__ Ahi,
                                                       float* __restrict__ out) {
    // [buf][ panel0: 4 oct x 256 col | panel1: 4 oct x 128 col ][8]  -> 24 KB per buf
    __shared__ ushort lds[3][1536 * 8];

    int bid = blockIdx.x;
    int swz = (bid % 8) * (SYRK_BLOCKS / 8) + bid / 8;   // XCD-chunked, bijective
    int b  = swz / 42;
    int p2 = swz % 42;
    int p = p2 >> 1, half = p2 & 1;
    int ti = 0;
    while ((ti + 1) * (ti + 2) / 2 <= p) ++ti;
    int tj = p - ti * (ti + 1) / 2;
    bool diag = (ti == tj);
    int i0 = ti * 256;
    int j0 = tj * 256 + half * 128;

    int t = threadIdx.x, w = t >> 6, l = t & 63;
    int wr = w >> 1, wc = w & 1;
    int lc = l & 15, lg = l >> 4;

    const ushort* base = Ahi + (size_t)b * 256 * N * 8;

    f32x4 acc[4][4];
#pragma unroll
    for (int i = 0; i < 4; ++i)
#pragma unroll
        for (int j = 0; j < 4; ++j)
#pragma unroll
            for (int k = 0; k < 4; ++k) acc[i][j][k] = 0.0f;

    // stage: i-panel always (2 loads/wave); j-panel only for non-diag (1 load/wave)
    auto stage = [&](int buf, int s) {
        ushort* Lb = lds[buf];
#pragma unroll
        for (int q = 0; q < 2; ++q) {           // i-panel: 1024 granules
            int g0 = q * 512 + w * 64;
            int oct = (g0 >> 8) & 3, col0 = g0 & 255;
            gload16(base + ((size_t)(s * 4 + oct) * N + i0 + col0 + l) * 8,
                    &Lb[(oct * 256 + col0) * 8]);
        }
        if (!diag) {                            // j-panel: 512 granules
            int oct = w >> 1, col0 = (w & 1) * 64;
            gload16(base + ((size_t)(s * 4 + oct) * N + j0 + col0 + l) * 8,
                    &Lb[1024 * 8 + (oct * 128 + col0) * 8]);
        }
    };

    int cur = 0, stg = 2;
    stage(0, 0);
    stage(1, 1);

    for (int s = 0; s < 64; ++s) {
        if (s < 62) {
            stage(stg, s + 2);                  // depth-2 lookahead stays in flight
            if (diag) asm volatile("s_waitcnt vmcnt(4)" ::: "memory");
            else      asm volatile("s_waitcnt vmcnt(6)" ::: "memory");
        } else if (s == 62) {
            if (diag) asm volatile("s_waitcnt vmcnt(2)" ::: "memory");
            else      asm volatile("s_waitcnt vmcnt(3)" ::: "memory");
        } else {
            asm volatile("s_waitcnt vmcnt(0)" ::: "memory");
        }
        __builtin_amdgcn_s_barrier();           // all waves' stage(s) complete
        asm volatile("" ::: "memory");          // pin ds_reads below the barrier

        const ushort* Lc = lds[cur];
        short8v Bv[4];
#pragma unroll
        for (int bj = 0; bj < 4; ++bj) {
            int cp = wc * 64 + bj * 16 + lc;
            const ushort* bp = diag ? &Lc[(lg * 256 + half * 128 + cp) * 8]
                                    : &Lc[1024 * 8 + (lg * 128 + cp) * 8];
            Bv[bj] = *(const short8v*)bp;
        }
        __builtin_amdgcn_s_setprio(1);
#pragma unroll
        for (int ai = 0; ai < 4; ++ai) {
            short8v Av = *(const short8v*)&Lc[(lg * 256 + wr * 64 + ai * 16 + lc) * 8];
#pragma unroll
            for (int bj = 0; bj < 4; ++bj)
                acc[ai][bj] = __builtin_amdgcn_mfma_f32_16x16x32_bf16(Av, Bv[bj], acc[ai][bj], 0, 0, 0);
        }
        __builtin_amdgcn_s_setprio(0);

        asm volatile("" ::: "memory");          // pin ds_reads above the end barrier
        __builtin_amdgcn_s_barrier();           // buf[cur] free before stage(s+3)
        cur = (cur + 1 == 3) ? 0 : cur + 1;
        stg = (stg + 1 == 3) ? 0 : stg + 1;
    }

    float* AtA = out + OFF_ATA + (size_t)b * N * N;
    float* Lo  = out + OFF_L   + (size_t)b * N * N;
    float* Up  = out + OFF_U   + (size_t)b * N * N;

#pragma unroll
    for (int ai = 0; ai < 4; ++ai) {
        int gi0 = i0 + wr * 64 + ai * 16 + lg * 4;
#pragma unroll
        for (int bj = 0; bj < 4; ++bj) {
            int gj = j0 + wc * 64 + bj * 16 + lc;
#pragma unroll
            for (int r = 0; r < 4; ++r) {
                int gi = gi0 + r;
                float v = acc[ai][bj][r];
                size_t o = (size_t)gi * N + gj;
                nts(v, AtA + o);
                nts((gj <= gi) ? v : 0.0f, Lo + o);
                nts((gj >  gi) ? v : 0.0f, Up + o);
            }
            if (!diag) {                        // mirror: float4 over r (contiguous gi)
                f32x4 va = acc[ai][bj], vl, vu;
#pragma unroll
                for (int r = 0; r < 4; ++r) {
                    int gi = gi0 + r;
                    vl[r] = (gi <= gj) ? va[r] : 0.0f;
                    vu[r] = (gi >  gj) ? va[r] : 0.0f;
                }
                size_t om = (size_t)gj * N + gi0;
                nts4(va, AtA + om);
                nts4(vl, Lo  + om);
                nts4(vu, Up  + om);
            }
        }
    }
}

// ---------------- fp32 fallback (round-1, known-good) ----------------
__global__ __launch_bounds__(256) void atp_d_kernel(const float* __restrict__ A,
                                                    const float* __restrict__ Arhs,
                                                    float* __restrict__ out) {
    int b  = blockIdx.x / 6;
    int cb = blockIdx.x % 6;
    int col = cb * 256 + threadIdx.x;
    const float* Ab = A + (size_t)b * M * N;
    const float* rb = Arhs + (size_t)b * M;
    float s1 = 0.0f, s2 = 0.0f;
#pragma unroll 4
    for (int m = 0; m < M; ++m) {
        float a = Ab[(size_t)m * N + col];
        float r = rb[m];
        s1 = fmaf(a, r, s1);
        s2 = fmaf(a, a, s2);
    }
    out[OFF_ATPRHS + b * N + col] = s1;
    out[OFF_D      + b * N + col] = s2;
}

#define BM 128
#define BK 16
#define NPAIRS 78

__global__ __launch_bounds__(256, 2) void syrk_kernel(const float* __restrict__ A,
                                                      float* __restrict__ out) {
    __shared__ float As[BK][BM];
    __shared__ float Bs[BK][BM];

    int bid = blockIdx.x;
    int b = bid / NPAIRS;
    int p = bid % NPAIRS;
    int ti = (int)((sqrtf(8.0f * (float)p + 1.0f) - 1.0f) * 0.5f);
    while ((ti + 1) * (ti + 2) / 2 <= p) ++ti;
    while (ti * (ti + 1) / 2 > p) --ti;
    int tj = p - ti * (ti + 1) / 2;
    int i0 = ti * BM, j0 = tj * BM;

    const float* Ab = A + (size_t)b * M * N;
    int t = threadIdx.x;
    int tx = t % 16, ty = t / 16;
    int lcv = (t % 32) * 4;
    int lk = t / 32;

    float acc[2][4][2][4] = {};

    for (int m0 = 0; m0 < M; m0 += BK) {
        const float* pa = Ab + (size_t)(m0 + lk) * N;
        float4 a0 = *(const float4*)(pa + i0 + lcv);
        float4 a1 = *(const float4*)(pa + (size_t)8 * N + i0 + lcv);
        float4 b0 = *(const float4*)(pa + j0 + lcv);
        float4 b1 = *(const float4*)(pa + (size_t)8 * N + j0 + lcv);
        *(float4*)&As[lk][lcv]     = a0;
        *(float4*)&As[lk + 8][lcv] = a1;
        *(float4*)&Bs[lk][lcv]     = b0;
        *(float4*)&Bs[lk + 8][lcv] = b1;
        __syncthreads();
#pragma unroll
        for (int kk = 0; kk < BK; ++kk) {
            float ar[2][4], br[2][4];
            *(float4*)&ar[0][0] = *(const float4*)&As[kk][ty * 4];
            *(float4*)&ar[1][0] = *(const float4*)&As[kk][64 + ty * 4];
            *(float4*)&br[0][0] = *(const float4*)&Bs[kk][tx * 4];
            *(float4*)&br[1][0] = *(const float4*)&Bs[kk][64 + tx * 4];
#pragma unroll
            for (int rh = 0; rh < 2; ++rh)
#pragma unroll
                for (int r = 0; r < 4; ++r)
#pragma unroll
                    for (int ch = 0; ch < 2; ++ch)
#pragma unroll
                        for (int c = 0; c < 4; ++c)
                            acc[rh][r][ch][c] = fmaf(ar[rh][r], br[ch][c], acc[rh][r][ch][c]);
        }
        __syncthreads();
    }

    float* AtA = out + OFF_ATA + (size_t)b * N * N;
    float* L   = out + OFF_L   + (size_t)b * N * N;
    float* U   = out + OFF_U   + (size_t)b * N * N;

#pragma unroll
    for (int rh = 0; rh < 2; ++rh)
#pragma unroll
        for (int r = 0; r < 4; ++r) {
            int gi = i0 + rh * 64 + ty * 4 + r;
#pragma unroll
            for (int ch = 0; ch < 2; ++ch) {
                int gjb = j0 + ch * 64 + tx * 4;
                float ta[4], tl[4], tu[4];
#pragma unroll
                for (int c = 0; c < 4; ++c) {
                    int gj = gjb + c;
                    float v = acc[rh][r][ch][c];
                    ta[c] = v;
                    tl[c] = (gj <= gi) ? v : 0.0f;
                    tu[c] = (gj >  gi) ? v : 0.0f;
                }
                size_t o = (size_t)gi * N + gjb;
                *(float4*)(AtA + o) = *(float4*)ta;
                *(float4*)(L   + o) = *(float4*)tl;
                *(float4*)(U   + o) = *(float4*)tu;
            }
        }

    if (ti != tj) {
#pragma unroll
        for (int ch = 0; ch < 2; ++ch)
#pragma unroll
            for (int c = 0; c < 4; ++c) {
                int gj = j0 + ch * 64 + tx * 4 + c;
#pragma unroll
                for (int rh = 0; rh < 2; ++rh) {
                    int gib = i0 + rh * 64 + ty * 4;
                    float ta[4], tl[4], tu[4];
#pragma unroll
                    for (int r = 0; r < 4; ++r) {
                        int gi = gib + r;
                        float v = acc[rh][r][ch][c];
                        ta[r] = v;
                        tl[r] = (gi <= gj) ? v : 0.0f;
                        tu[r] = (gi >  gj) ? v : 0.0f;
                    }
                    size_t o = (size_t)gj * N + gib;
                    *(float4*)(AtA + o) = *(float4*)ta;
                    *(float4*)(L   + o) = *(float4*)tl;
                    *(float4*)(U   + o) = *(float4*)tu;
                }
            }
    }
}

extern "C" void kernel_launch(void* const* d_in, const int* in_sizes, int n_in,
                              void* d_out, int out_size, void* d_ws, size_t ws_size,
                              hipStream_t stream) {
    const float* coeffs = (const float*)d_in[0];
    const float* rhs    = (const float*)d_in[1];
    const float* sx     = (const float*)d_in[2];
    const float* sy     = (const float*)d_in[3];
    const float* A      = (const float*)d_in[4];
    const float* Arhs   = (const float*)d_in[5];
    float* out = (float*)d_out;

    small_kernel<<<(SMALL_TOTAL + 255) / 256, 256, 0, stream>>>(coeffs, rhs, sx, sy, out);

    const size_t hi_bytes   = (size_t)NB * M * N * sizeof(ushort);       // 201,326,592
    const size_t part_bytes = (size_t)4 * NB * 6 * 256 * sizeof(float2); // 1,572,864
    if (ws_size >= hi_bytes + part_bytes) {
        ushort* Ahi  = (ushort*)d_ws;
        float2* part = (float2*)((char*)d_ws + hi_bytes);
        split_kernel<<<768, 256, 0, stream>>>(A, Arhs, Ahi, part);
        reduce_kernel<<<192, 256, 0, stream>>>(part, out);
        syrk1_kernel<<<SYRK_BLOCKS, 512, 0, stream>>>(Ahi, out);
    } else {
        atp_d_kernel<<<NB * 6, 256, 0, stream>>>(A, Arhs, out);
        syrk_kernel<<<NB * NPAIRS, 256, 0, stream>>>(A, out);
    }
}